// Round 3
// baseline (495.714 us; speedup 1.0000x reference)
//
#include <hip/hip_runtime.h>

// Graph message passing: out = nf + mean_{e: tgt(e)=v}(nf[src(e)] + nf[v]), residual.
// Simplification: dest-term per segment = cnt[v]*nf[v], folded into finalize.
// Phase 1: scatter-add src rows with device-scope f32 atomics (wave-per-edge, lane=feature).
// Phase 2: elementwise finalize.

#define D 64

// ws layout: [0, n_nodes) int counts, [n_nodes] int is64 flag.

__global__ void detect_idx_width(const int* __restrict__ ei, int* __restrict__ flag) {
    // int64 little-endian indices < 2^31 have all odd 32-bit words == 0.
    // P(64 random int32 indices in [0,100000) all being 0) ~ 1e-320: safe.
    if (blockIdx.x == 0 && threadIdx.x == 0) {
        int allzero = 1;
        for (int i = 0; i < 64; ++i) {
            if (ei[2 * i + 1] != 0) { allzero = 0; break; }
        }
        *flag = allzero;
    }
}

__global__ __launch_bounds__(256) void edge_scatter(
        const float* __restrict__ nf,
        const int* __restrict__ ei,      // edge_index as 32-bit words
        const int* __restrict__ flag,    // 1 if underlying dtype is int64
        float* __restrict__ agg,         // accumulator (= d_out), pre-zeroed
        int* __restrict__ cnt,           // per-node in-degree, pre-zeroed
        int n_edges) {
    const int lane = threadIdx.x & 63;
    const int wave = (int)((blockIdx.x * (unsigned)blockDim.x + threadIdx.x) >> 6);
    const int nwaves = (int)((gridDim.x * (unsigned)blockDim.x) >> 6);

    if (*flag != 0) {
        // int64 indices: low word at 2*e (src) / 2*(E+e) (tgt).
        for (int e = wave; e < n_edges; e += nwaves) {
            int s = ei[2 * (size_t)e];
            int t = ei[2 * ((size_t)n_edges + e)];
            float v = nf[(size_t)s * D + lane];        // 256B coalesced row gather (L3-resident)
            atomicAdd(&agg[(size_t)t * D + lane], v);  // 64-lane consecutive-address f32 atomic
            if (lane == 0) atomicAdd(&cnt[t], 1);
        }
    } else {
        // int32 indices.
        for (int e = wave; e < n_edges; e += nwaves) {
            int s = ei[e];
            int t = ei[(size_t)n_edges + e];
            float v = nf[(size_t)s * D + lane];
            atomicAdd(&agg[(size_t)t * D + lane], v);
            if (lane == 0) atomicAdd(&cnt[t], 1);
        }
    }
}

__global__ __launch_bounds__(256) void finalize(
        const float* __restrict__ nf,
        const int* __restrict__ cnt,
        float* __restrict__ out,         // in: agg sums; out: final
        int n_elems) {
    int i = blockIdx.x * blockDim.x + threadIdx.x;   // element index over n_nodes*D
    if (i >= n_elems) return;
    int v = i >> 6;                                   // node id (D == 64)
    float c = (float)cnt[v];
    float inv = (c > 0.f) ? (1.0f / c) : 1.0f;
    float self = nf[i];
    float scale = (c > 0.f) ? 2.0f : 1.0f;            // nf + cnt*nf/cnt == 2*nf when cnt>0
    out[i] = self * scale + out[i] * inv;
}

extern "C" void kernel_launch(void* const* d_in, const int* in_sizes, int n_in,
                              void* d_out, int out_size, void* d_ws, size_t ws_size,
                              hipStream_t stream) {
    const float* nf = (const float*)d_in[0];
    const int* ei = (const int*)d_in[1];
    float* out = (float*)d_out;

    const int n_nodes = in_sizes[0] / D;      // 100000
    const int n_edges = in_sizes[1] / 2;      // 1600000 (elem count halves the same for i32/i64)

    int* cnt = (int*)d_ws;
    int* flag = cnt + n_nodes;

    // Zero accumulator (d_out doubles as agg buffer) and counts+flag.
    hipMemsetAsync(d_out, 0, (size_t)out_size * sizeof(float), stream);
    hipMemsetAsync(d_ws, 0, ((size_t)n_nodes + 1) * sizeof(int), stream);

    detect_idx_width<<<1, 64, 0, stream>>>(ei, flag);

    // 2048 blocks * 4 waves = 8192 waves = full 256CU*32wave residency; ~196 edges/wave.
    edge_scatter<<<2048, 256, 0, stream>>>(nf, ei, flag, out, cnt, n_edges);

    const int n_elems = n_nodes * D;
    finalize<<<(n_elems + 255) / 256, 256, 0, stream>>>(nf, cnt, out, n_elems);
}

// Round 4
// 342.188 us; speedup vs baseline: 1.4487x; 1.4487x over previous
//
#include <hip/hip_runtime.h>

// Graph message passing: out = nf + mean_{e: tgt(e)=v}(nf[src(e)] + nf[v]), residual.
// dest-term telescopes: sum_{e:tgt=v} nf[v] = cnt[v]*nf[v], folded into epilogue:
//   out[v] = nf[v]*(cnt>0?2:1) + (sum_{e:tgt=v} nf[src(e)]) / max(cnt,1)
//
// Round 3 showed f32-atomic scatter is the bottleneck (400us, WRITE_SIZE=450MB,
// VALUBusy 7%). This version builds a CSR permutation (int atomics only) and
// aggregates gather-side: no float atomics, d_out written exactly once.

#define D 64
#define SCAN_BLOCK 1024

// ---------- shared helpers ----------

__global__ void detect_idx_width(const int* __restrict__ ei, int* __restrict__ flag) {
    // int64 little-endian indices < 2^31 have all odd 32-bit words == 0.
    if (blockIdx.x == 0 && threadIdx.x == 0) {
        int allzero = 1;
        for (int i = 0; i < 64; ++i) {
            if (ei[2 * i + 1] != 0) { allzero = 0; break; }
        }
        *flag = allzero;
    }
}

__device__ __forceinline__ int load_src(const int* ei, int e, int n_edges, bool is64) {
    return is64 ? ei[2 * (size_t)e] : ei[e];
}
__device__ __forceinline__ int load_tgt(const int* ei, int e, int n_edges, bool is64) {
    return is64 ? ei[2 * ((size_t)n_edges + e)] : ei[(size_t)n_edges + e];
}

// ---------- CSR path ----------

__global__ __launch_bounds__(256) void histogram(
        const int* __restrict__ ei, const int* __restrict__ flag,
        int* __restrict__ cnt, int n_edges) {
    const bool is64 = (*flag != 0);
    int i = blockIdx.x * blockDim.x + threadIdx.x;
    int stride = gridDim.x * blockDim.x;
    for (int e = i; e < n_edges; e += stride) {
        atomicAdd(&cnt[load_tgt(ei, e, n_edges, is64)], 1);
    }
}

// Per-chunk exclusive scan (chunk = SCAN_BLOCK elems), block totals to bsum.
__global__ __launch_bounds__(SCAN_BLOCK) void scan_chunks(
        const int* __restrict__ cnt, int* __restrict__ rowptr,
        int* __restrict__ bsum, int n) {
    __shared__ int lds[SCAN_BLOCK];
    int tid = threadIdx.x;
    int gid = blockIdx.x * SCAN_BLOCK + tid;
    int v = (gid < n) ? cnt[gid] : 0;
    lds[tid] = v;
    __syncthreads();
    for (int off = 1; off < SCAN_BLOCK; off <<= 1) {   // Hillis-Steele inclusive
        int add = (tid >= off) ? lds[tid - off] : 0;
        __syncthreads();
        lds[tid] += add;
        __syncthreads();
    }
    if (gid < n) rowptr[gid] = lds[tid] - v;           // exclusive
    if (tid == SCAN_BLOCK - 1) bsum[blockIdx.x] = lds[tid];
}

// Exclusive scan of block sums (nb <= SCAN_BLOCK), in place.
__global__ __launch_bounds__(SCAN_BLOCK) void scan_bsums(int* __restrict__ bsum, int nb) {
    __shared__ int lds[SCAN_BLOCK];
    int tid = threadIdx.x;
    int v = (tid < nb) ? bsum[tid] : 0;
    lds[tid] = v;
    __syncthreads();
    for (int off = 1; off < SCAN_BLOCK; off <<= 1) {
        int add = (tid >= off) ? lds[tid - off] : 0;
        __syncthreads();
        lds[tid] += add;
        __syncthreads();
    }
    if (tid < nb) bsum[tid] = lds[tid] - v;
}

__global__ __launch_bounds__(256) void add_offsets(
        int* __restrict__ rowptr, const int* __restrict__ bsum, int n) {
    int i = blockIdx.x * blockDim.x + threadIdx.x;
    if (i < n) rowptr[i] += bsum[i >> 10];             // SCAN_BLOCK == 1024
}

__global__ __launch_bounds__(256) void fill_perm(
        const int* __restrict__ ei, const int* __restrict__ flag,
        const int* __restrict__ rowptr, int* __restrict__ cur,
        int* __restrict__ perm, int n_edges) {
    const bool is64 = (*flag != 0);
    int i = blockIdx.x * blockDim.x + threadIdx.x;
    int stride = gridDim.x * blockDim.x;
    for (int e = i; e < n_edges; e += stride) {
        int s = load_src(ei, e, n_edges, is64);
        int t = load_tgt(ei, e, n_edges, is64);
        int pos = atomicAdd(&cur[t], 1);
        perm[rowptr[t] + pos] = s;
    }
}

// One wave per node: sum perm-listed src rows (lane = feature), fused epilogue.
__global__ __launch_bounds__(256) void aggregate(
        const float* __restrict__ nf, const int* __restrict__ rowptr,
        const int* __restrict__ cnt, const int* __restrict__ perm,
        float* __restrict__ out, int n_nodes) {
    const int lane = threadIdx.x & 63;
    const int v = (int)((blockIdx.x * (unsigned)blockDim.x + threadIdx.x) >> 6);
    if (v >= n_nodes) return;
    const int start = rowptr[v];
    const int c = cnt[v];
    float sum0 = 0.f, sum1 = 0.f;                      // 2-way ILP on the gather chain
    int j = 0;
    for (; j + 1 < c; j += 2) {
        int s0 = perm[start + j];
        int s1 = perm[start + j + 1];
        sum0 += nf[(size_t)s0 * D + lane];
        sum1 += nf[(size_t)s1 * D + lane];
    }
    if (j < c) sum0 += nf[(size_t)perm[start + j] * D + lane];
    float self = nf[(size_t)v * D + lane];
    float scale = (c > 0) ? 2.0f : 1.0f;
    float inv = (c > 0) ? (1.0f / (float)c) : 1.0f;
    out[(size_t)v * D + lane] = self * scale + (sum0 + sum1) * inv;
}

// ---------- fallback atomic path (Round-3, known-correct) ----------

__global__ __launch_bounds__(256) void edge_scatter(
        const float* __restrict__ nf, const int* __restrict__ ei,
        const int* __restrict__ flag, float* __restrict__ agg,
        int* __restrict__ cnt, int n_edges) {
    const bool is64 = (*flag != 0);
    const int lane = threadIdx.x & 63;
    const int wave = (int)((blockIdx.x * (unsigned)blockDim.x + threadIdx.x) >> 6);
    const int nwaves = (int)((gridDim.x * (unsigned)blockDim.x) >> 6);
    for (int e = wave; e < n_edges; e += nwaves) {
        int s = load_src(ei, e, n_edges, is64);
        int t = load_tgt(ei, e, n_edges, is64);
        atomicAdd(&agg[(size_t)t * D + lane], nf[(size_t)s * D + lane]);
        if (lane == 0) atomicAdd(&cnt[t], 1);
    }
}

__global__ __launch_bounds__(256) void finalize(
        const float* __restrict__ nf, const int* __restrict__ cnt,
        float* __restrict__ out, int n_elems) {
    int i = blockIdx.x * blockDim.x + threadIdx.x;
    if (i >= n_elems) return;
    int v = i >> 6;
    float c = (float)cnt[v];
    float inv = (c > 0.f) ? (1.0f / c) : 1.0f;
    float scale = (c > 0.f) ? 2.0f : 1.0f;
    out[i] = nf[i] * scale + out[i] * inv;
}

// ---------- launch ----------

extern "C" void kernel_launch(void* const* d_in, const int* in_sizes, int n_in,
                              void* d_out, int out_size, void* d_ws, size_t ws_size,
                              hipStream_t stream) {
    const float* nf = (const float*)d_in[0];
    const int* ei = (const int*)d_in[1];
    float* out = (float*)d_out;

    const int n_nodes = in_sizes[0] / D;      // 100000
    const int n_edges = in_sizes[1] / 2;      // 1600000

    const int nb = (n_nodes + SCAN_BLOCK - 1) / SCAN_BLOCK;   // scan chunks (98)

    // ws layout (ints): cnt[N] | cur[N] | bsum[nb] | flag | rowptr[N] | perm[E]
    int* cnt    = (int*)d_ws;
    int* cur    = cnt + n_nodes;
    int* bsum   = cur + n_nodes;
    int* flag   = bsum + nb;
    int* rowptr = flag + 1;
    int* perm   = rowptr + n_nodes;
    const size_t need = ((size_t)3 * n_nodes + nb + 1 + n_edges) * sizeof(int);

    if (ws_size >= need && nb <= SCAN_BLOCK) {
        // CSR path: zero cnt+cur+bsum+flag, build CSR, aggregate gather-side.
        hipMemsetAsync(d_ws, 0, ((size_t)2 * n_nodes + nb + 1) * sizeof(int), stream);
        detect_idx_width<<<1, 64, 0, stream>>>(ei, flag);
        histogram<<<2048, 256, 0, stream>>>(ei, flag, cnt, n_edges);
        scan_chunks<<<nb, SCAN_BLOCK, 0, stream>>>(cnt, rowptr, bsum, n_nodes);
        scan_bsums<<<1, SCAN_BLOCK, 0, stream>>>(bsum, nb);
        add_offsets<<<(n_nodes + 255) / 256, 256, 0, stream>>>(rowptr, bsum, n_nodes);
        fill_perm<<<2048, 256, 0, stream>>>(ei, flag, rowptr, cur, perm, n_edges);
        const int agg_blocks = (n_nodes * 64 + 255) / 256;    // wave per node
        aggregate<<<agg_blocks, 256, 0, stream>>>(nf, rowptr, cnt, perm, out, n_nodes);
    } else {
        // Fallback: Round-3 atomic path.
        hipMemsetAsync(d_out, 0, (size_t)out_size * sizeof(float), stream);
        hipMemsetAsync(d_ws, 0, ((size_t)n_nodes + 1) * sizeof(int), stream);
        int* fcnt = (int*)d_ws;
        int* fflag = fcnt + n_nodes;
        detect_idx_width<<<1, 64, 0, stream>>>(ei, fflag);
        edge_scatter<<<2048, 256, 0, stream>>>(nf, ei, fflag, out, fcnt, n_edges);
        finalize<<<(n_nodes * 64 + 255) / 256, 256, 0, stream>>>(nf, fcnt, out, n_nodes * 64);
    }
}